// Round 1
// baseline (94.720 us; speedup 1.0000x reference)
//
#include <hip/hip_runtime.h>
#include <cstdint>

// Lukasiewicz max-plus matmul: y[n,o] = max(b[o], max(0, max_i(x[n,i]+a[o,i]-1)))
// N=2048 rows, K=512 inner, M=512 out cols. All fp32.
//
// VALU-bound (no max-plus MFMA exists). 64x64 tile / 256 thr / 4x4 per thread,
// BK=64 double-buffered LDS staged via global_load_lds(16B), XOR-swizzled
// (both-sides: inverse-swizzled global source + swizzled ds_read offsets).

#define TILE 64
#define BK   64
#define NROW 2048
#define NK   512
#define NCOL 512

__device__ __forceinline__ void async_load16(const float* g, float* l) {
  __builtin_amdgcn_global_load_lds(
      (const __attribute__((address_space(1))) void*)g,
      (__attribute__((address_space(3))) void*)l,
      16, 0, 0);
}

__global__ __launch_bounds__(256) void luka_kernel(
    const float* __restrict__ X, const float* __restrict__ A,
    const float* __restrict__ Bv, float* __restrict__ Y) {
  // [buf][row*64 + swizzled_k] ; 4 x 16KB = 64KB LDS
  __shared__ float xs[2][TILE * BK];
  __shared__ float as[2][TILE * BK];

  const int tid  = threadIdx.x;
  const int wave = tid >> 6;
  const int tx   = tid & 15;   // col group
  const int ty   = tid >> 4;   // row group
  const int rowBase = blockIdx.y * TILE;
  const int colBase = blockIdx.x * TILE;

  // Swizzle mask m(row) = (row&15) ^ (row>>2). Chosen so that:
  //  - x-frag reads (rows ty*4+r, r=0..3): 4 distinct slots  -> conflict-free
  //  - a-frag reads (rows tx*4+c, tx=0..15): 16 distinct slots -> 2-way max (free)
  uint32_t xoff[4], aoff[4];   // precomputed byte offsets (row*256 | m<<4)
#pragma unroll
  for (int r = 0; r < 4; ++r) {
    int row = ty * 4 + r;
    uint32_t m = (uint32_t)((row & 15) ^ (row >> 2));
    xoff[r] = (uint32_t)row * 256u + (m << 4);
  }
#pragma unroll
  for (int c = 0; c < 4; ++c) {
    int row = tx * 4 + c;
    uint32_t m = (uint32_t)((row & 15) ^ (row >> 2));
    aoff[c] = (uint32_t)row * 256u + (m << 4);
  }

  float acc[4][4];
#pragma unroll
  for (int r = 0; r < 4; ++r)
#pragma unroll
    for (int c = 0; c < 4; ++c) acc[r][c] = 0.0f;  // folds the ReLU clamp

  const int row0 = tid >> 4;  // 0..15
  const int sl   = tid & 15;  // float4 slot within a row's 64 floats

  // Stage one BK-tile of x and a. LDS dest is linear (wave-uniform base +
  // lane*16, per global_load_lds HW rule); the swizzle is applied by
  // permuting the GLOBAL source element each lane fetches (rule #21).
  auto stage = [&](int buf, int kt) {
#pragma unroll
    for (int j = 0; j < 4; ++j) {
      int row = row0 + j * 16;
      int m   = (row & 15) ^ (row >> 2);
      int kk  = ((sl ^ m) << 2);
      const float* gx = X + (size_t)(rowBase + row) * NK + kt * BK + kk;
      const float* ga = A + (size_t)(colBase + row) * NK + kt * BK + kk;
      async_load16(gx, &xs[buf][j * 1024 + wave * 256]);
      async_load16(ga, &as[buf][j * 1024 + wave * 256]);
    }
  };

  stage(0, 0);
  __syncthreads();

  int buf = 0;
#pragma unroll 1
  for (int kt = 0; kt < NK / BK; ++kt) {
    if (kt < NK / BK - 1) stage(buf ^ 1, kt + 1);  // prefetch next tile

    const char* xb = (const char*)&xs[buf][0];
    const char* ab = (const char*)&as[buf][0];
#pragma unroll
    for (int s4 = 0; s4 < BK / 4; ++s4) {
      float4 xf[4], af[4];
#pragma unroll
      for (int r = 0; r < 4; ++r)
        xf[r] = *(const float4*)(xb + (xoff[r] ^ (uint32_t)(s4 << 4)));
#pragma unroll
      for (int c = 0; c < 4; ++c)
        af[c] = *(const float4*)(ab + (aoff[c] ^ (uint32_t)(s4 << 4)));
#pragma unroll
      for (int r = 0; r < 4; ++r) {
#pragma unroll
        for (int c = 0; c < 4; ++c) {
          float s0 = xf[r].x + af[c].x;
          float s1 = xf[r].y + af[c].y;
          float s2 = xf[r].z + af[c].z;
          float s3 = xf[r].w + af[c].w;
          float t  = fmaxf(fmaxf(s0, s1), s2);          // v_max3 candidate
          acc[r][c] = fmaxf(fmaxf(t, s3), acc[r][c]);   // v_max3 candidate
        }
      }
    }
    __syncthreads();  // drains vmcnt -> prefetched tile resident; buf reusable
    buf ^= 1;
  }

  // Epilogue: y = max(max(acc - 1, 0), b)   (deferring -1 is exact: rounding
  // is monotone, so max commutes with (.-1))
  const float4 bv = *(const float4*)&Bv[colBase + tx * 4];
#pragma unroll
  for (int r = 0; r < 4; ++r) {
    float4 o;
    o.x = fmaxf(fmaxf(acc[r][0] - 1.0f, 0.0f), bv.x);
    o.y = fmaxf(fmaxf(acc[r][1] - 1.0f, 0.0f), bv.y);
    o.z = fmaxf(fmaxf(acc[r][2] - 1.0f, 0.0f), bv.z);
    o.w = fmaxf(fmaxf(acc[r][3] - 1.0f, 0.0f), bv.w);
    *(float4*)&Y[(size_t)(rowBase + ty * 4 + r) * NCOL + colBase + tx * 4] = o;
  }
}

extern "C" void kernel_launch(void* const* d_in, const int* in_sizes, int n_in,
                              void* d_out, int out_size, void* d_ws, size_t ws_size,
                              hipStream_t stream) {
  const float* X = (const float*)d_in[0];   // [2048][512]
  const float* A = (const float*)d_in[1];   // [512][512]
  const float* B = (const float*)d_in[2];   // [512]
  float* Y = (float*)d_out;                 // [2048][512]
  dim3 grid(NCOL / TILE, NROW / TILE);      // (8, 32) = 256 blocks, 1/CU
  luka_kernel<<<grid, dim3(256), 0, stream>>>(X, A, B, Y);
}